// Round 1
// baseline (694.138 us; speedup 1.0000x reference)
//
#include <hip/hip_runtime.h>

// ---------------------------------------------------------------------------
// GCN link predictor, fp32 baseline.
// Pipeline: degree+CSR build -> XW1 -> agg+bias+relu -> H1W2 -> agg+bias ->
//           per-edge MLP decoder.
// ---------------------------------------------------------------------------

__global__ void count_deg_k(const int* __restrict__ dst, int* __restrict__ cnt, int E) {
    int i = blockIdx.x * 256 + threadIdx.x;
    if (i < E) atomicAdd(&cnt[dst[i]], 1);
}

__global__ void dinv_k(const int* __restrict__ cnt, float* __restrict__ dinv, int n) {
    int i = blockIdx.x * 256 + threadIdx.x;
    if (i < n) dinv[i] = rsqrtf((float)cnt[i] + 1.0f);  // +1 = self-loop
}

// Block-level exclusive scan (1024 elems/block of 256 threads, 4 per thread).
__global__ void scan1_k(const int* __restrict__ cnt, int* __restrict__ excl,
                        int* __restrict__ bsum, int n) {
    __shared__ int sd[256];
    int t = threadIdx.x;
    int base = blockIdx.x * 1024 + t * 4;
    int v0 = 0, v1 = 0, v2 = 0, v3 = 0;
    if (base + 0 < n) v0 = cnt[base + 0];
    if (base + 1 < n) v1 = cnt[base + 1];
    if (base + 2 < n) v2 = cnt[base + 2];
    if (base + 3 < n) v3 = cnt[base + 3];
    int sum = v0 + v1 + v2 + v3;
    int acc = sum;
    sd[t] = acc;
    __syncthreads();
    for (int off = 1; off < 256; off <<= 1) {
        int x = (t >= off) ? sd[t - off] : 0;
        __syncthreads();
        acc += x;
        sd[t] = acc;
        __syncthreads();
    }
    int run = acc - sum;  // exclusive prefix of this thread's chunk
    if (base + 0 < n) excl[base + 0] = run;
    run += v0;
    if (base + 1 < n) excl[base + 1] = run;
    run += v1;
    if (base + 2 < n) excl[base + 2] = run;
    run += v2;
    if (base + 3 < n) excl[base + 3] = run;
    if (t == 255) bsum[blockIdx.x] = acc;  // block total
}

__global__ void scan2_k(int* __restrict__ bsum, int nb) {
    __shared__ int sd[256];
    int t = threadIdx.x;
    int v = (t < nb) ? bsum[t] : 0;
    int acc = v;
    sd[t] = acc;
    __syncthreads();
    for (int off = 1; off < 256; off <<= 1) {
        int x = (t >= off) ? sd[t - off] : 0;
        __syncthreads();
        acc += x;
        sd[t] = acc;
        __syncthreads();
    }
    if (t < nb) bsum[t] = acc - v;  // exclusive block offsets
}

__global__ void scan3_k(int* __restrict__ excl, const int* __restrict__ bsum,
                        int* __restrict__ cursor, int n) {
    int i = blockIdx.x * 256 + threadIdx.x;
    if (i < n) {
        int v = excl[i] + bsum[i >> 10];
        excl[i] = v;
        cursor[i] = v;
    }
}

__global__ void scatter_k(const int* __restrict__ src, const int* __restrict__ dst,
                          int* __restrict__ cursor, int* __restrict__ csr_src, int E) {
    int i = blockIdx.x * 256 + threadIdx.x;
    if (i < E) {
        int d = dst[i];
        int p = atomicAdd(&cursor[d], 1);
        csr_src[p] = src[i];
    }
}

// ---------------------------------------------------------------------------
// C[M,NCOL] = A[M,128] @ W[128,NCOL].  Tile 64 rows x NCOL cols.
// Per-thread 4 rows x 8 cols, k-unroll 4. Threads = 16*(NCOL/8).
// ---------------------------------------------------------------------------
template <int NCOL>
__global__ void gemm_k(const float* __restrict__ A, const float* __restrict__ W,
                       float* __restrict__ C, int M) {
    constexpr int CG = NCOL / 8;   // col groups
    constexpr int NT = 16 * CG;    // threads
    __shared__ float Xs[64][68];   // +4 pad: breaks 4-way bank conflict on row reads
    __shared__ float Ws[64][NCOL];
    const int t = threadIdx.x;
    const int rg = t / CG;
    const int cg = t % CG;
    const int row0 = blockIdx.x * 64;

    float acc[4][8];
#pragma unroll
    for (int i = 0; i < 4; ++i)
#pragma unroll
        for (int j = 0; j < 8; ++j) acc[i][j] = 0.f;

    for (int kh = 0; kh < 128; kh += 64) {
        // stage X tile (64 rows x 64 k)
#pragma unroll
        for (int i = 0; i < 4096 / (NT * 4); ++i) {
            int li = (i * NT + t) * 4;
            int r = li >> 6, c = li & 63;
            int gr = row0 + r;
            if (gr >= M) gr = M - 1;  // clamp; stores guarded
            float4 v = *(const float4*)(A + (size_t)gr * 128 + kh + c);
            *(float4*)(&Xs[r][c]) = v;
        }
        // stage W tile (64 k x NCOL)
#pragma unroll
        for (int i = 0; i < (64 * NCOL) / (NT * 4); ++i) {
            int li = (i * NT + t) * 4;
            int r = li / NCOL, c = li % NCOL;
            float4 v = *(const float4*)(W + (size_t)(kh + r) * NCOL + c);
            *(float4*)(&Ws[r][c]) = v;
        }
        __syncthreads();

#pragma unroll
        for (int k4 = 0; k4 < 16; ++k4) {
            const int k = k4 * 4;
            float xr[4][4];
#pragma unroll
            for (int i = 0; i < 4; ++i) {
                float4 tmp = *(const float4*)(&Xs[rg * 4 + i][k]);
                xr[i][0] = tmp.x; xr[i][1] = tmp.y; xr[i][2] = tmp.z; xr[i][3] = tmp.w;
            }
#pragma unroll
            for (int kk = 0; kk < 4; ++kk) {
                const float* wr = &Ws[k + kk][cg * 8];
                float wv[8];
#pragma unroll
                for (int j = 0; j < 8; ++j) wv[j] = wr[j];
#pragma unroll
                for (int i = 0; i < 4; ++i) {
                    float x = xr[i][kk];
#pragma unroll
                    for (int j = 0; j < 8; ++j) acc[i][j] = fmaf(x, wv[j], acc[i][j]);
                }
            }
        }
        __syncthreads();
    }

#pragma unroll
    for (int i = 0; i < 4; ++i) {
        int gr = row0 + rg * 4 + i;
        if (gr < M) {
            float* cp = C + (size_t)gr * NCOL + cg * 8;
            float4 v0, v1;
            v0.x = acc[i][0]; v0.y = acc[i][1]; v0.z = acc[i][2]; v0.w = acc[i][3];
            v1.x = acc[i][4]; v1.y = acc[i][5]; v1.z = acc[i][6]; v1.w = acc[i][7];
            *(float4*)cp = v0;
            *(float4*)(cp + 4) = v1;
        }
    }
}

// ---------------------------------------------------------------------------
// GCN aggregation: out[n] = sum_{e:dst=n} dinv[src]*dinv[n]*XW[src]
//                         + dinv[n]^2*XW[n] + bias  (optional ReLU)
// One wave per node; lane covers 2 features (D=128) or 1 (D=64).
// ---------------------------------------------------------------------------
template <int D, bool RELU>
__global__ void agg_k(const float* __restrict__ XW, const float* __restrict__ dinv,
                      const int* __restrict__ row_start, const int* __restrict__ cnt,
                      const int* __restrict__ csr_src, const float* __restrict__ bias,
                      float* __restrict__ out, int n) {
    int wid = (int)((blockIdx.x * blockDim.x + threadIdx.x) >> 6);
    int lane = threadIdx.x & 63;
    if (wid >= n) return;
    float di = dinv[wid];
    int deg = cnt[wid];
    int rs = row_start[wid];
    if constexpr (D == 128) {
        float2 a = ((const float2*)(XW + (size_t)wid * 128))[lane];
        float sn = di * di;
        float ax = a.x * sn, ay = a.y * sn;
        for (int i = 0; i < deg; ++i) {
            int s = csr_src[rs + i];
            float nm = dinv[s] * di;
            float2 v = ((const float2*)(XW + (size_t)s * 128))[lane];
            ax = fmaf(v.x, nm, ax);
            ay = fmaf(v.y, nm, ay);
        }
        float2 b = ((const float2*)bias)[lane];
        ax += b.x;
        ay += b.y;
        if (RELU) { ax = fmaxf(ax, 0.f); ay = fmaxf(ay, 0.f); }
        float2 r; r.x = ax; r.y = ay;
        ((float2*)(out + (size_t)wid * 128))[lane] = r;
    } else {
        float a = XW[(size_t)wid * 64 + lane] * (di * di);
        for (int i = 0; i < deg; ++i) {
            int s = csr_src[rs + i];
            a = fmaf(XW[(size_t)s * 64 + lane], dinv[s] * di, a);
        }
        a += bias[lane];
        if (RELU) a = fmaxf(a, 0.f);
        out[(size_t)wid * 64 + lane] = a;
    }
}

// ---------------------------------------------------------------------------
// Decoder: per edge e, z = [H2[src], H2[dst]] (128), h = relu(z@Wm1+bm1) (64),
// out[e] = h@Wm2 + bm2.  One wave per edge iteration; lane j owns Wm1 col j
// in 128 VGPRs; z read as uniform-address float4 loads; butterfly reduce.
// ---------------------------------------------------------------------------
__global__ __launch_bounds__(256, 2) void decoder_k(
    const float* __restrict__ H2, const int* __restrict__ esrc, const int* __restrict__ edst,
    const float* __restrict__ Wm1, const float* __restrict__ bm1,
    const float* __restrict__ Wm2, const float* __restrict__ bm2,
    float* __restrict__ out, int E) {
    const int lane = threadIdx.x & 63;
    const int wid = (int)((blockIdx.x * blockDim.x + threadIdx.x) >> 6);
    const int nw = (int)((gridDim.x * blockDim.x) >> 6);

    float w[128];
#pragma unroll
    for (int k = 0; k < 128; ++k) w[k] = Wm1[k * 64 + lane];
    const float b1 = bm1[lane];
    const float w2 = Wm2[lane];
    const float b2 = bm2[0];

    for (int e = wid; e < E; e += nw) {
        int s = __builtin_amdgcn_readfirstlane(esrc[e]);
        int d = __builtin_amdgcn_readfirstlane(edst[e]);
        const float* zs = H2 + (size_t)s * 64;
        const float* zd = H2 + (size_t)d * 64;
        float a0 = 0.f, a1 = 0.f, a2 = 0.f, a3 = 0.f;
#pragma unroll
        for (int k4 = 0; k4 < 32; ++k4) {
            const float* zp = (k4 < 16) ? (zs + k4 * 4) : (zd + (k4 - 16) * 4);
            float4 z = *(const float4*)zp;
            a0 = fmaf(z.x, w[k4 * 4 + 0], a0);
            a1 = fmaf(z.y, w[k4 * 4 + 1], a1);
            a2 = fmaf(z.z, w[k4 * 4 + 2], a2);
            a3 = fmaf(z.w, w[k4 * 4 + 3], a3);
        }
        float h = a0 + a1 + a2 + a3 + b1;
        h = fmaxf(h, 0.f);
        float p = h * w2;
#pragma unroll
        for (int off = 32; off; off >>= 1) p += __shfl_xor(p, off, 64);
        if (lane == 0) out[e] = p + b2;
    }
}

// ---------------------------------------------------------------------------

extern "C" void kernel_launch(void* const* d_in, const int* in_sizes, int n_in,
                              void* d_out, int out_size, void* d_ws, size_t ws_size,
                              hipStream_t stream) {
    const float* X   = (const float*)d_in[0];
    const int*  edges = (const int*)d_in[1];
    const float* Wg1 = (const float*)d_in[2];
    const float* bg1 = (const float*)d_in[3];
    const float* Wg2 = (const float*)d_in[4];
    const float* bg2 = (const float*)d_in[5];
    const float* Wm1 = (const float*)d_in[6];
    const float* bm1 = (const float*)d_in[7];
    const float* Wm2 = (const float*)d_in[8];
    const float* bm2 = (const float*)d_in[9];
    float* out = (float*)d_out;

    const int N = in_sizes[0] / 128;
    const int E = in_sizes[1] / 2;
    const int* esrc = edges;
    const int* edst = edges + E;

    char* p = (char*)d_ws;
    auto alloc = [&](size_t nbytes) {
        void* r = (void*)p;
        p += (nbytes + 255) & ~(size_t)255;
        return r;
    };
    float* XW1  = (float*)alloc((size_t)N * 128 * 4);
    float* H1   = (float*)alloc((size_t)N * 128 * 4);
    float* HW2  = (float*)alloc((size_t)N * 64 * 4);
    float* H2   = (float*)alloc((size_t)N * 64 * 4);
    float* dinv = (float*)alloc((size_t)N * 4);
    int* cnt    = (int*)alloc((size_t)N * 4);
    int* rowst  = (int*)alloc((size_t)N * 4);
    int* cursor = (int*)alloc((size_t)N * 4);
    int* bsum   = (int*)alloc(1024);
    int* csr    = (int*)alloc((size_t)E * 4);
    (void)ws_size; (void)n_in; (void)out_size;

    const int gE = (E + 255) / 256;
    const int gN = (N + 255) / 256;
    const int nb = (N + 1023) / 1024;
    const int gM = (N + 63) / 64;
    const int gAgg = (N * 64 + 255) / 256;

    hipMemsetAsync(cnt, 0, (size_t)N * 4, stream);
    count_deg_k<<<gE, 256, 0, stream>>>(edst, cnt, E);
    dinv_k<<<gN, 256, 0, stream>>>(cnt, dinv, N);
    scan1_k<<<nb, 256, 0, stream>>>(cnt, rowst, bsum, N);
    scan2_k<<<1, 256, 0, stream>>>(bsum, nb);
    scan3_k<<<gN, 256, 0, stream>>>(rowst, bsum, cursor, N);
    scatter_k<<<gE, 256, 0, stream>>>(esrc, edst, cursor, csr, E);

    gemm_k<128><<<gM, 256, 0, stream>>>(X, Wg1, XW1, N);
    agg_k<128, true><<<gAgg, 256, 0, stream>>>(XW1, dinv, rowst, cnt, csr, bg1, H1, N);
    gemm_k<64><<<gM, 128, 0, stream>>>(H1, Wg2, HW2, N);
    agg_k<64, false><<<gAgg, 256, 0, stream>>>(HW2, dinv, rowst, cnt, csr, bg2, H2, N);
    decoder_k<<<2048, 256, 0, stream>>>(H2, esrc, edst, Wm1, bm1, Wm2, bm2, out, E);
}